// Round 1
// 581.572 us; speedup vs baseline: 1.0962x; 1.0962x over previous
//
#include <hip/hip_runtime.h>
#include <math.h>

#define BB 16
#define SS 4096
#define HH 1024
#define SCH 64    // s-chunk for weighted-sum kernel

// d_ws layout:
//   [0, 4 MB)            : W tiled hi/lo bf16: [ct(8)][kc(32)] blocks of 16 KB
//                          each block: hi 8 KB = n(128) x k(32) bf16 (XOR-swizzled
//                          slot layout, see below), then lo 8 KB
//   [4 MB, 4 MB + 256 KB): scores / attn probs, B*S fp32 (atomicAdd target)
//
// LDS fragment layout (A and B identical): row r (0..127) occupies 64 B,
// split into 4 slots of 16 B. Element k (0..31) lives at
//   byte = r*64 + (SWZ(r, k>>3))*16 + (k&7)*2,  SWZ(r,s) = s ^ ((r>>1)&3)
// Every 8 consecutive lanes of a ds_read_b128 / ds_write_b64 then cover all
// 8 bank-quads -> conflict-free.

typedef __attribute__((ext_vector_type(8))) short bf16x8;
typedef __attribute__((ext_vector_type(16))) float f32x16;

__device__ __forceinline__ void gl_lds16(const void* g, void* l) {
  __builtin_amdgcn_global_load_lds(
      (const __attribute__((address_space(1))) void*)g,
      (__attribute__((address_space(3))) void*)l, 16, 0, 0);
}

// ---- W -> tiled hi/lo bf16 (truncation split), swizzled slot layout --------
__global__ __launch_bounds__(256) void conv_w(const float* __restrict__ W,
                                              unsigned short* __restrict__ Bbuf) {
  int ct = blockIdx.x, kc = blockIdx.y;
  unsigned short* blk = Bbuf + (size_t)(ct * 32 + kc) * 8192;  // 16 KB / 2
  int tid = threadIdx.x;
#pragma unroll
  for (int it = 0; it < 16; ++it) {
    int flat = it * 256 + tid;
    int n = flat >> 5, kk = flat & 31;
    float f = W[(size_t)(ct * 128 + n) * HH + kc * 32 + kk];
    unsigned u = __float_as_uint(f);
    float hf = __uint_as_float(u & 0xffff0000u);
    int slot = (kk >> 3) ^ ((n >> 1) & 3);
    int idx = n * 32 + slot * 8 + (kk & 7);
    blk[idx] = (unsigned short)(u >> 16);
    blk[4096 + idx] = (unsigned short)(__float_as_uint(f - hf) >> 16);
  }
}

// ---- scores GEMM: 3-stream split-bf16 MFMA, fused tanh.key epilogue --------
// grid (8, 512) flat-swizzled so all 8 col-tiles of a row-tile land on ONE XCD
// (L2 reuse of the 512 KB x row-tile), round-robin over t for load balance.
// Double-buffered LDS (64 KB): A0|B0|A1|B1, one barrier per K-step.
__global__ __launch_bounds__(256, 2) void scores_gemm(
    const float* __restrict__ x, const int* __restrict__ lengths,
    const unsigned short* __restrict__ Bbuf, const float* __restrict__ bias,
    const float* __restrict__ key, float* __restrict__ scores) {
  // ---- XCD-aware bijective swizzle ----
  // hw flat id f -> XCD f%8 (round-robin). Keep all 8 ct of a given t at the
  // same residue mod 8 (same XCD), with t round-robined across XCDs:
  //   r = f&7, j = f>>3;  t = r + (j & ~7);  ct = j & 7
  int f = blockIdx.y * 8 + blockIdx.x;
  int r8 = f & 7, j = f >> 3;
  int t = r8 + (j & ~7);
  int ct = j & 7;
  int b = t >> 5;
  int s0 = (t & 31) * 128;
  if (s0 >= lengths[b]) return;   // softmax/wsum never read s >= L

  __shared__ char lds[65536];
  char* A0 = lds;              // 16 KB (hi 8 + lo 8)
  char* B0 = lds + 16384;      // 16 KB
  char* A1 = lds + 32768;
  char* B1 = lds + 49152;

  int tid = threadIdx.x;
  int lane = tid & 63, w = tid >> 6;
  int wm = w & 1, wn = w >> 1;

  f32x16 acc[2][2];
#pragma unroll
  for (int mt = 0; mt < 2; ++mt)
#pragma unroll
    for (int nt = 0; nt < 2; ++nt)
#pragma unroll
      for (int i = 0; i < 16; ++i) acc[mt][nt][i] = 0.f;

  const float* xb = x + ((size_t)b * SS + s0) * HH;
  const char* Bblk0 = (const char*)Bbuf + (size_t)ct * 32 * 16384;

  int ar = tid >> 3;            // staging row 0..31 (+32*it)
  int ak8 = tid & 7;            // k-octet index (4 elements)
  // swizzled A-write byte offset within row ((row>>1)&3 invariant under +32)
  int awoff = (((ak8 >> 1) ^ ((ar >> 1) & 3)) << 4) + ((ak8 & 1) << 3);

  int mrow = lane & 31;         // MFMA m (and n) index
  int khsel = lane >> 5;        // which 8-k half of a 16-k fragment
  int rx = (mrow >> 1) & 3;
  int soff0 = ((khsel ^ rx)) << 4;        // kh=0 slot byte offset
  int soff1 = (((2 + khsel) ^ rx)) << 4;  // kh=1 slot byte offset
  int rbA = (wm * 64 + mrow) * 64;
  int rbB = (wn * 64 + mrow) * 64;

  float4 v[4];

#define STAGE_ISSUE(KC, BDST)                                              \
  {                                                                        \
    const char* Bblk = Bblk0 + (KC) * 16384;                               \
    _Pragma("unroll") for (int i = 0; i < 4; ++i) {                        \
      int c = w * 4 + i;                                                   \
      gl_lds16(Bblk + c * 1024 + lane * 16, (BDST) + c * 1024);            \
    }                                                                      \
    _Pragma("unroll") for (int it = 0; it < 4; ++it)                       \
      v[it] = *(const float4*)(xb + (size_t)(ar + it * 32) * HH +          \
                               (KC) * 32 + ak8 * 4);                       \
  }

#define A_WRITE(ADST)                                                      \
  {                                                                        \
    _Pragma("unroll") for (int it = 0; it < 4; ++it) {                     \
      int rr = ar + it * 32;                                               \
      unsigned u0 = __float_as_uint(v[it].x), u1 = __float_as_uint(v[it].y);\
      unsigned u2 = __float_as_uint(v[it].z), u3 = __float_as_uint(v[it].w);\
      float l0 = v[it].x - __uint_as_float(u0 & 0xffff0000u);              \
      float l1 = v[it].y - __uint_as_float(u1 & 0xffff0000u);              \
      float l2 = v[it].z - __uint_as_float(u2 & 0xffff0000u);              \
      float l3 = v[it].w - __uint_as_float(u3 & 0xffff0000u);              \
      uint2 hp, lp;                                                        \
      hp.x = (u0 >> 16) | (u1 & 0xffff0000u);                              \
      hp.y = (u2 >> 16) | (u3 & 0xffff0000u);                              \
      lp.x = (__float_as_uint(l0) >> 16) | (__float_as_uint(l1) & 0xffff0000u);\
      lp.y = (__float_as_uint(l2) >> 16) | (__float_as_uint(l3) & 0xffff0000u);\
      *(uint2*)((ADST) + rr * 64 + awoff) = hp;                            \
      *(uint2*)((ADST) + 8192 + rr * 64 + awoff) = lp;                     \
    }                                                                      \
  }

#define COMPUTE(AC, BC)                                                    \
  {                                                                        \
    _Pragma("unroll") for (int kh = 0; kh < 2; ++kh) {                     \
      int so = kh ? soff1 : soff0;                                         \
      bf16x8 ah[2], al[2], bh[2], bl[2];                                   \
      _Pragma("unroll") for (int mt = 0; mt < 2; ++mt) {                   \
        ah[mt] = *(bf16x8*)((AC) + rbA + mt * 2048 + so);                  \
        al[mt] = *(bf16x8*)((AC) + 8192 + rbA + mt * 2048 + so);           \
        bh[mt] = *(bf16x8*)((BC) + rbB + mt * 2048 + so);                  \
        bl[mt] = *(bf16x8*)((BC) + 8192 + rbB + mt * 2048 + so);           \
      }                                                                    \
      _Pragma("unroll") for (int mt = 0; mt < 2; ++mt)                     \
        _Pragma("unroll") for (int nt = 0; nt < 2; ++nt) {                 \
          acc[mt][nt] = __builtin_amdgcn_mfma_f32_32x32x16_bf16(           \
              ah[mt], bh[nt], acc[mt][nt], 0, 0, 0);                       \
          acc[mt][nt] = __builtin_amdgcn_mfma_f32_32x32x16_bf16(           \
              ah[mt], bl[nt], acc[mt][nt], 0, 0, 0);                       \
          acc[mt][nt] = __builtin_amdgcn_mfma_f32_32x32x16_bf16(           \
              al[mt], bh[nt], acc[mt][nt], 0, 0, 0);                       \
        }                                                                  \
    }                                                                      \
  }

  // prologue: stage K-step 0 into buf0
  STAGE_ISSUE(0, B0)
  A_WRITE(A0)
  __syncthreads();

  for (int kc = 0; kc < 32; kc += 2) {
    // phase A: compute buf0(kc), stage buf1(kc+1) underneath
    STAGE_ISSUE(kc + 1, B1)
    COMPUTE(A0, B0)
    A_WRITE(A1)
    __syncthreads();
    // phase B: compute buf1(kc+1), stage buf0(kc+2) underneath
    if (kc + 2 < 32) { STAGE_ISSUE(kc + 2, B0) }
    COMPUTE(A1, B1)
    if (kc + 2 < 32) { A_WRITE(A0) }
    __syncthreads();
  }

#undef STAGE_ISSUE
#undef A_WRITE
#undef COMPUTE

  // --- epilogue: score[row] += sum_o tanh(pre + bias[o]) * key[o]
  // C/D map (32x32): col = lane&31, row = (reg&3) + 8*(reg>>2) + 4*(lane>>5)
  int col = lane & 31;
  int rbase = (lane >> 5) * 4;
  float bo[2], ko[2];
#pragma unroll
  for (int nt = 0; nt < 2; ++nt) {
    int o = ct * 128 + wn * 64 + nt * 32 + col;
    bo[nt] = bias[o];
    ko[nt] = key[o];
  }
  float* srow = scores + (size_t)b * SS + s0;
#pragma unroll
  for (int mt = 0; mt < 2; ++mt) {
#pragma unroll
    for (int reg = 0; reg < 16; ++reg) {
      float sv = tanhf(acc[mt][0][reg] + bo[0]) * ko[0] +
                 tanhf(acc[mt][1][reg] + bo[1]) * ko[1];
#pragma unroll
      for (int off = 1; off < 32; off <<= 1) sv += __shfl_xor(sv, off);
      if (col == 0) {
        int row = wm * 64 + mt * 32 + (reg & 3) + 8 * (reg >> 2) + rbase;
        atomicAdd(srow + row, sv);
      }
    }
  }
}

// ---- masked softmax over s < L, in place -----------------------------------
__global__ __launch_bounds__(1024) void softmax_kernel(float* __restrict__ sc,
                                                       const int* __restrict__ lengths) {
  int b = blockIdx.x;
  int L = lengths[b];
  float* p = sc + (size_t)b * SS;
  __shared__ float sred[18];
  int tid = threadIdx.x;

  float m = -3.0e38f;
  for (int s = tid; s < L; s += 1024) m = fmaxf(m, p[s]);
  for (int off = 32; off > 0; off >>= 1) m = fmaxf(m, __shfl_down(m, off));
  if ((tid & 63) == 0) sred[tid >> 6] = m;
  __syncthreads();
  if (tid == 0) {
    float mm = sred[0];
    for (int w = 1; w < 16; ++w) mm = fmaxf(mm, sred[w]);
    sred[16] = mm;
  }
  __syncthreads();
  m = sred[16];

  float z = 0.f;
  for (int s = tid; s < L; s += 1024) {
    float e = expf(p[s] - m);
    p[s] = e;           // cache exp, saves a recompute pass
    z += e;
  }
  for (int off = 32; off > 0; off >>= 1) z += __shfl_down(z, off);
  if ((tid & 63) == 0) sred[tid >> 6] = z;
  __syncthreads();
  if (tid == 0) {
    float zz = 0.f;
    for (int w = 0; w < 16; ++w) zz += sred[w];
    sred[17] = zz;
  }
  __syncthreads();
  float inv = 1.f / sred[17];
  for (int s = tid; s < L; s += 1024) p[s] *= inv;
}

// ---- out[b,h] = sum_{s<L} p[b,s] * x[b,s,h] --------------------------------
// batch 8 s-steps -> 8 independent x float4 loads + 2 p float4 loads in
// flight per iteration (was 1; loop was memory-latency serialized)
__global__ __launch_bounds__(256) void wsum_kernel(const float* __restrict__ x,
                                                   const float* __restrict__ p,
                                                   const int* __restrict__ lengths,
                                                   float* __restrict__ out) {
  int b = blockIdx.y;
  int L = lengths[b];
  int sbeg = blockIdx.x * SCH;
  if (sbeg >= L) return;
  int send = min(sbeg + SCH, L);
  int h = threadIdx.x * 4;
  const float* xb = x + (size_t)b * SS * HH + h;
  const float* pb = p + (size_t)b * SS;
  float4 acc = {0.f, 0.f, 0.f, 0.f};
  int s = sbeg;
  for (; s + 8 <= send; s += 8) {
    float4 pa = *(const float4*)(pb + s);
    float4 pc = *(const float4*)(pb + s + 4);
    float4 vv[8];
#pragma unroll
    for (int jj = 0; jj < 8; ++jj)
      vv[jj] = *(const float4*)(xb + (size_t)(s + jj) * HH);
    float pw[8] = {pa.x, pa.y, pa.z, pa.w, pc.x, pc.y, pc.z, pc.w};
#pragma unroll
    for (int jj = 0; jj < 8; ++jj) {
      acc.x = fmaf(pw[jj], vv[jj].x, acc.x);
      acc.y = fmaf(pw[jj], vv[jj].y, acc.y);
      acc.z = fmaf(pw[jj], vv[jj].z, acc.z);
      acc.w = fmaf(pw[jj], vv[jj].w, acc.w);
    }
  }
  for (; s < send; ++s) {
    float wgt = pb[s];
    float4 vx = *(const float4*)(xb + (size_t)s * HH);
    acc.x = fmaf(wgt, vx.x, acc.x);
    acc.y = fmaf(wgt, vx.y, acc.y);
    acc.z = fmaf(wgt, vx.z, acc.z);
    acc.w = fmaf(wgt, vx.w, acc.w);
  }
  float* o = out + (size_t)b * HH + h;
  atomicAdd(o + 0, acc.x);
  atomicAdd(o + 1, acc.y);
  atomicAdd(o + 2, acc.z);
  atomicAdd(o + 3, acc.w);
}

extern "C" void kernel_launch(void* const* d_in, const int* in_sizes, int n_in,
                              void* d_out, int out_size, void* d_ws, size_t ws_size,
                              hipStream_t stream) {
  const float* x = (const float*)d_in[0];
  const int* lengths = (const int*)d_in[1];
  const float* W = (const float*)d_in[2];
  const float* bias = (const float*)d_in[3];
  const float* key = (const float*)d_in[4];
  float* out = (float*)d_out;

  unsigned short* Bbuf = (unsigned short*)d_ws;                    // 4 MB
  float* scores = (float*)((char*)d_ws + (size_t)4 * 1024 * 1024); // 256 KB

  hipMemsetAsync(d_out, 0, (size_t)out_size * sizeof(float), stream);
  hipMemsetAsync(scores, 0, (size_t)BB * SS * sizeof(float), stream);
  conv_w<<<dim3(8, 32), 256, 0, stream>>>(W, Bbuf);
  scores_gemm<<<dim3(8, 512), 256, 0, stream>>>(x, lengths, Bbuf, bias, key, scores);
  softmax_kernel<<<dim3(BB), 1024, 0, stream>>>(scores, lengths);
  wsum_kernel<<<dim3(SS / SCH, BB), 256, 0, stream>>>(x, scores, lengths, out);
}

// Round 3
// 580.785 us; speedup vs baseline: 1.0977x; 1.0014x over previous
//
#include <hip/hip_runtime.h>
#include <math.h>

#define BB 16
#define SS 4096
#define HH 1024
#define SCH 64    // s-chunk for weighted-sum kernel (SS/SCH = 64 chunks)

// d_ws layout:
//   [0, 4 MB)            : phase 1 (scores_gemm): W tiled hi/lo bf16,
//                          [ct(8)][kc(32)] blocks of 16 KB
//                          phase 2 (wsum): partial sums [b(16)][chunk(64)][h(1024)] f32
//                          (Bbuf is dead after scores_gemm; stream order makes reuse safe)
//   [4 MB, 4 MB + 256 KB): scores / attn probs, B*S fp32 (atomicAdd target)
//
// LDS fragment layout (A and B identical): row r (0..127) occupies 64 B,
// split into 4 slots of 16 B. Element k (0..31) lives at
//   byte = r*64 + (SWZ(r, k>>3))*16 + (k&7)*2,  SWZ(r,s) = s ^ ((r>>1)&3)
// Every 8 consecutive lanes of a ds_read_b128 / ds_write_b64 then cover all
// 8 bank-quads -> conflict-free.

typedef __attribute__((ext_vector_type(8))) short bf16x8;
typedef __attribute__((ext_vector_type(16))) float f32x16;

__device__ __forceinline__ void gl_lds16(const void* g, void* l) {
  __builtin_amdgcn_global_load_lds(
      (const __attribute__((address_space(1))) void*)g,
      (__attribute__((address_space(3))) void*)l, 16, 0, 0);
}

// ---- W -> tiled hi/lo bf16 (truncation split), swizzled slot layout --------
__global__ __launch_bounds__(256) void conv_w(const float* __restrict__ W,
                                              unsigned short* __restrict__ Bbuf) {
  int ct = blockIdx.x, kc = blockIdx.y;
  unsigned short* blk = Bbuf + (size_t)(ct * 32 + kc) * 8192;  // 16 KB / 2
  int tid = threadIdx.x;
#pragma unroll
  for (int it = 0; it < 16; ++it) {
    int flat = it * 256 + tid;
    int n = flat >> 5, kk = flat & 31;
    float f = W[(size_t)(ct * 128 + n) * HH + kc * 32 + kk];
    unsigned u = __float_as_uint(f);
    float hf = __uint_as_float(u & 0xffff0000u);
    int slot = (kk >> 3) ^ ((n >> 1) & 3);
    int idx = n * 32 + slot * 8 + (kk & 7);
    blk[idx] = (unsigned short)(u >> 16);
    blk[4096 + idx] = (unsigned short)(__float_as_uint(f - hf) >> 16);
  }
}

// ---- scores GEMM: 3-stream split-bf16 MFMA, fused tanh.key epilogue --------
// grid (8, 512) flat-swizzled so all 8 col-tiles of a row-tile land on ONE XCD
// (L2 reuse of the 512 KB x row-tile), round-robin over t for load balance.
// Double-buffered LDS (64 KB): A0|B0|A1|B1, one barrier per K-step.
// NOTE: at the measured 2-phase structural ceiling (~700 TF eq.); next lever
// is the 8-phase counted-vmcnt schedule, kept out of this round on purpose.
__global__ __launch_bounds__(256, 2) void scores_gemm(
    const float* __restrict__ x, const int* __restrict__ lengths,
    const unsigned short* __restrict__ Bbuf, const float* __restrict__ bias,
    const float* __restrict__ key, float* __restrict__ scores) {
  // ---- XCD-aware bijective swizzle ----
  int f = blockIdx.y * 8 + blockIdx.x;
  int r8 = f & 7, j = f >> 3;
  int t = r8 + (j & ~7);
  int ct = j & 7;
  int b = t >> 5;
  int s0 = (t & 31) * 128;
  if (s0 >= lengths[b]) return;   // softmax/wsum never read s >= L

  __shared__ char lds[65536];
  char* A0 = lds;              // 16 KB (hi 8 + lo 8)
  char* B0 = lds + 16384;      // 16 KB
  char* A1 = lds + 32768;
  char* B1 = lds + 49152;

  int tid = threadIdx.x;
  int lane = tid & 63, w = tid >> 6;
  int wm = w & 1, wn = w >> 1;

  f32x16 acc[2][2];
#pragma unroll
  for (int mt = 0; mt < 2; ++mt)
#pragma unroll
    for (int nt = 0; nt < 2; ++nt)
#pragma unroll
      for (int i = 0; i < 16; ++i) acc[mt][nt][i] = 0.f;

  const float* xb = x + ((size_t)b * SS + s0) * HH;
  const char* Bblk0 = (const char*)Bbuf + (size_t)ct * 32 * 16384;

  int ar = tid >> 3;            // staging row 0..31 (+32*it)
  int ak8 = tid & 7;            // k-octet index (4 elements)
  int awoff = (((ak8 >> 1) ^ ((ar >> 1) & 3)) << 4) + ((ak8 & 1) << 3);

  int mrow = lane & 31;         // MFMA m (and n) index
  int khsel = lane >> 5;        // which 8-k half of a 16-k fragment
  int rx = (mrow >> 1) & 3;
  int soff0 = ((khsel ^ rx)) << 4;        // kh=0 slot byte offset
  int soff1 = (((2 + khsel) ^ rx)) << 4;  // kh=1 slot byte offset
  int rbA = (wm * 64 + mrow) * 64;
  int rbB = (wn * 64 + mrow) * 64;

  float4 v[4];

#define STAGE_ISSUE(KC, BDST)                                              \
  {                                                                        \
    const char* Bblk = Bblk0 + (KC) * 16384;                               \
    _Pragma("unroll") for (int i = 0; i < 4; ++i) {                        \
      int c = w * 4 + i;                                                   \
      gl_lds16(Bblk + c * 1024 + lane * 16, (BDST) + c * 1024);            \
    }                                                                      \
    _Pragma("unroll") for (int it = 0; it < 4; ++it)                       \
      v[it] = *(const float4*)(xb + (size_t)(ar + it * 32) * HH +          \
                               (KC) * 32 + ak8 * 4);                       \
  }

#define A_WRITE(ADST)                                                      \
  {                                                                        \
    _Pragma("unroll") for (int it = 0; it < 4; ++it) {                     \
      int rr = ar + it * 32;                                               \
      unsigned u0 = __float_as_uint(v[it].x), u1 = __float_as_uint(v[it].y);\
      unsigned u2 = __float_as_uint(v[it].z), u3 = __float_as_uint(v[it].w);\
      float l0 = v[it].x - __uint_as_float(u0 & 0xffff0000u);              \
      float l1 = v[it].y - __uint_as_float(u1 & 0xffff0000u);              \
      float l2 = v[it].z - __uint_as_float(u2 & 0xffff0000u);              \
      float l3 = v[it].w - __uint_as_float(u3 & 0xffff0000u);              \
      uint2 hp, lp;                                                        \
      hp.x = (u0 >> 16) | (u1 & 0xffff0000u);                              \
      hp.y = (u2 >> 16) | (u3 & 0xffff0000u);                              \
      lp.x = (__float_as_uint(l0) >> 16) | (__float_as_uint(l1) & 0xffff0000u);\
      lp.y = (__float_as_uint(l2) >> 16) | (__float_as_uint(l3) & 0xffff0000u);\
      *(uint2*)((ADST) + rr * 64 + awoff) = hp;                            \
      *(uint2*)((ADST) + 8192 + rr * 64 + awoff) = lp;                     \
    }                                                                      \
  }

#define COMPUTE(AC, BC)                                                    \
  {                                                                        \
    _Pragma("unroll") for (int kh = 0; kh < 2; ++kh) {                     \
      int so = kh ? soff1 : soff0;                                         \
      bf16x8 ah[2], al[2], bh[2], bl[2];                                   \
      _Pragma("unroll") for (int mt = 0; mt < 2; ++mt) {                   \
        ah[mt] = *(bf16x8*)((AC) + rbA + mt * 2048 + so);                  \
        al[mt] = *(bf16x8*)((AC) + 8192 + rbA + mt * 2048 + so);           \
        bh[mt] = *(bf16x8*)((BC) + rbB + mt * 2048 + so);                  \
        bl[mt] = *(bf16x8*)((BC) + 8192 + rbB + mt * 2048 + so);           \
      }                                                                    \
      _Pragma("unroll") for (int mt = 0; mt < 2; ++mt)                     \
        _Pragma("unroll") for (int nt = 0; nt < 2; ++nt) {                 \
          acc[mt][nt] = __builtin_amdgcn_mfma_f32_32x32x16_bf16(           \
              ah[mt], bh[nt], acc[mt][nt], 0, 0, 0);                       \
          acc[mt][nt] = __builtin_amdgcn_mfma_f32_32x32x16_bf16(           \
              ah[mt], bl[nt], acc[mt][nt], 0, 0, 0);                       \
          acc[mt][nt] = __builtin_amdgcn_mfma_f32_32x32x16_bf16(           \
              al[mt], bh[nt], acc[mt][nt], 0, 0, 0);                       \
        }                                                                  \
    }                                                                      \
  }

  // prologue: stage K-step 0 into buf0
  STAGE_ISSUE(0, B0)
  A_WRITE(A0)
  __syncthreads();

  for (int kc = 0; kc < 32; kc += 2) {
    STAGE_ISSUE(kc + 1, B1)
    COMPUTE(A0, B0)
    A_WRITE(A1)
    __syncthreads();
    if (kc + 2 < 32) { STAGE_ISSUE(kc + 2, B0) }
    COMPUTE(A1, B1)
    if (kc + 2 < 32) { A_WRITE(A0) }
    __syncthreads();
  }

#undef STAGE_ISSUE
#undef A_WRITE
#undef COMPUTE

  // --- epilogue: score[row] += sum_o tanh(pre + bias[o]) * key[o]
  int col = lane & 31;
  int rbase = (lane >> 5) * 4;
  float bo[2], ko[2];
#pragma unroll
  for (int nt = 0; nt < 2; ++nt) {
    int o = ct * 128 + wn * 64 + nt * 32 + col;
    bo[nt] = bias[o];
    ko[nt] = key[o];
  }
  float* srow = scores + (size_t)b * SS + s0;
#pragma unroll
  for (int mt = 0; mt < 2; ++mt) {
#pragma unroll
    for (int reg = 0; reg < 16; ++reg) {
      float sv = tanhf(acc[mt][0][reg] + bo[0]) * ko[0] +
                 tanhf(acc[mt][1][reg] + bo[1]) * ko[1];
#pragma unroll
      for (int off = 1; off < 32; off <<= 1) sv += __shfl_xor(sv, off);
      if (col == 0) {
        int row = wm * 64 + mt * 32 + (reg & 3) + 8 * (reg >> 2) + rbase;
        atomicAdd(srow + row, sv);
      }
    }
  }
}

// ---- masked softmax over s < L, in place -----------------------------------
__global__ __launch_bounds__(1024) void softmax_kernel(float* __restrict__ sc,
                                                       const int* __restrict__ lengths) {
  int b = blockIdx.x;
  int L = lengths[b];
  float* p = sc + (size_t)b * SS;
  __shared__ float sred[18];
  int tid = threadIdx.x;

  float m = -3.0e38f;
  for (int s = tid; s < L; s += 1024) m = fmaxf(m, p[s]);
  for (int off = 32; off > 0; off >>= 1) m = fmaxf(m, __shfl_down(m, off));
  if ((tid & 63) == 0) sred[tid >> 6] = m;
  __syncthreads();
  if (tid == 0) {
    float mm = sred[0];
    for (int w = 1; w < 16; ++w) mm = fmaxf(mm, sred[w]);
    sred[16] = mm;
  }
  __syncthreads();
  m = sred[16];

  float z = 0.f;
  for (int s = tid; s < L; s += 1024) {
    float e = expf(p[s] - m);
    p[s] = e;           // cache exp, saves a recompute pass
    z += e;
  }
  for (int off = 32; off > 0; off >>= 1) z += __shfl_down(z, off);
  if ((tid & 63) == 0) sred[tid >> 6] = z;
  __syncthreads();
  if (tid == 0) {
    float zz = 0.f;
    for (int w = 0; w < 16; ++w) zz += sred[w];
    sred[17] = zz;
  }
  __syncthreads();
  float inv = 1.f / sred[17];
  for (int s = tid; s < L; s += 1024) p[s] *= inv;
}

// ---- stage 1: part[b][c][h] = sum_{s in chunk c, s<L} p[b,s] * x[b,s,h] ----
// plain float4 stores into the (dead) Bbuf region -> zero atomics.
// Blocks whose chunk is entirely >= L exit; their slots hold garbage that
// stage 2 never reads (predicated on lengths).
__global__ __launch_bounds__(256) void wsum_partial(const float* __restrict__ x,
                                                    const float* __restrict__ p,
                                                    const int* __restrict__ lengths,
                                                    float* __restrict__ part) {
  int b = blockIdx.y;
  int L = lengths[b];
  int c = blockIdx.x;
  int sbeg = c * SCH;
  if (sbeg >= L) return;
  int send = min(sbeg + SCH, L);
  int h = threadIdx.x * 4;
  const float* xb = x + (size_t)b * SS * HH + h;
  const float* pb = p + (size_t)b * SS;
  float4 acc = {0.f, 0.f, 0.f, 0.f};
  int s = sbeg;
  for (; s + 8 <= send; s += 8) {
    float4 pa = *(const float4*)(pb + s);
    float4 pc = *(const float4*)(pb + s + 4);
    float4 vv[8];
#pragma unroll
    for (int jj = 0; jj < 8; ++jj)
      vv[jj] = *(const float4*)(xb + (size_t)(s + jj) * HH);
    float pw[8] = {pa.x, pa.y, pa.z, pa.w, pc.x, pc.y, pc.z, pc.w};
#pragma unroll
    for (int jj = 0; jj < 8; ++jj) {
      acc.x = fmaf(pw[jj], vv[jj].x, acc.x);
      acc.y = fmaf(pw[jj], vv[jj].y, acc.y);
      acc.z = fmaf(pw[jj], vv[jj].z, acc.z);
      acc.w = fmaf(pw[jj], vv[jj].w, acc.w);
    }
  }
  for (; s < send; ++s) {
    float wgt = pb[s];
    float4 vx = *(const float4*)(xb + (size_t)s * HH);
    acc.x = fmaf(wgt, vx.x, acc.x);
    acc.y = fmaf(wgt, vx.y, acc.y);
    acc.z = fmaf(wgt, vx.z, acc.z);
    acc.w = fmaf(wgt, vx.w, acc.w);
  }
  *(float4*)(part + ((size_t)b * (SS / SCH) + c) * HH + h) = acc;
}

// ---- stage 2: out[b][h] = sum_{c valid} part[b][c][h] ----------------------
__global__ __launch_bounds__(256) void wsum_reduce(const float* __restrict__ part,
                                                   const int* __restrict__ lengths,
                                                   float* __restrict__ out) {
  int b = blockIdx.x;
  int nc = (lengths[b] + SCH - 1) / SCH;   // number of valid chunks
  int h = threadIdx.x * 4;
  const float* pb = part + (size_t)b * (SS / SCH) * HH + h;
  float4 acc = {0.f, 0.f, 0.f, 0.f};
  int c = 0;
  for (; c + 8 <= nc; c += 8) {
    float4 v[8];
#pragma unroll
    for (int j = 0; j < 8; ++j) v[j] = *(const float4*)(pb + (size_t)(c + j) * HH);
#pragma unroll
    for (int j = 0; j < 8; ++j) {
      acc.x += v[j].x; acc.y += v[j].y; acc.z += v[j].z; acc.w += v[j].w;
    }
  }
  for (; c < nc; ++c) {
    float4 v = *(const float4*)(pb + (size_t)c * HH);
    acc.x += v.x; acc.y += v.y; acc.z += v.z; acc.w += v.w;
  }
  *(float4*)(out + (size_t)b * HH + h) = acc;
}

extern "C" void kernel_launch(void* const* d_in, const int* in_sizes, int n_in,
                              void* d_out, int out_size, void* d_ws, size_t ws_size,
                              hipStream_t stream) {
  const float* x = (const float*)d_in[0];
  const int* lengths = (const int*)d_in[1];
  const float* W = (const float*)d_in[2];
  const float* bias = (const float*)d_in[3];
  const float* key = (const float*)d_in[4];
  float* out = (float*)d_out;

  unsigned short* Bbuf = (unsigned short*)d_ws;                    // 4 MB
  float* part = (float*)d_ws;                                      // reused after gemm
  float* scores = (float*)((char*)d_ws + (size_t)4 * 1024 * 1024); // 256 KB

  hipMemsetAsync(scores, 0, (size_t)BB * SS * sizeof(float), stream);
  conv_w<<<dim3(8, 32), 256, 0, stream>>>(W, Bbuf);
  scores_gemm<<<dim3(8, 512), 256, 0, stream>>>(x, lengths, Bbuf, bias, key, scores);
  softmax_kernel<<<dim3(BB), 1024, 0, stream>>>(scores, lengths);
  wsum_partial<<<dim3(SS / SCH, BB), 256, 0, stream>>>(x, scores, lengths, part);
  wsum_reduce<<<dim3(BB), 256, 0, stream>>>(part, lengths, out);
}